// Round 1
// baseline (638.847 us; speedup 1.0000x reference)
//
#include <hip/hip_runtime.h>
#include <math.h>

#define TPB 256

#define NTOT 32768      // 8*16*16*16 samples
#define KCB  1024       // codebook size
#define DDIM 256        // e_dim
#define SPAT 4096       // 16^3 spatial per batch
#define ZBATCH 1048576  // 256*4096 floats per batch

#define INV_EPS 20.0f   // 1/0.05
#define INV_T   10.0f   // 1/0.1

// ---------------- init ----------------
__global__ __launch_bounds__(TPB) void vq_init_kernel(float* __restrict__ bvec, float* __restrict__ R,
                                                      int* __restrict__ counts, float* __restrict__ loss){
    int t = blockIdx.x * TPB + threadIdx.x;
    if (t < NTOT) bvec[t] = 1.0f;
    if (t < 3*KCB) R[t] = 0.0f;
    if (t < KCB) counts[t] = 0;
    if (t == 0) loss[0] = 0.0f;
}

// ---------------- row norms of zf ----------------
__global__ __launch_bounds__(TPB) void vq_norms_kernel(const float* __restrict__ z, float* __restrict__ invn){
    int n = blockIdx.x * TPB + threadIdx.x;
    int b = n >> 12, s = n & 4095;
    const float* zp = z + (size_t)b * ZBATCH + s;
    float sum = 0.0f;
    #pragma unroll 8
    for (int c = 0; c < DDIM; ++c){
        float v = zp[(size_t)c * SPAT];
        sum += v * v;
    }
    invn[n] = 1.0f / fmaxf(sqrtf(sum), 1e-12f);
}

// ---------------- fp32 GEMM: L[n][k] = invn[n] * sum_c zf[n][c]*W[k][c] ----------------
__global__ __launch_bounds__(TPB) void vq_gemm_kernel(const float* __restrict__ z, const float* __restrict__ W,
                                                      const float* __restrict__ invn, float* __restrict__ L){
    __shared__ float As[32][128];
    __shared__ float Bs[32][132];   // pad to cut ds_write conflicts
    int tid = threadIdx.x;
    int k0 = blockIdx.x * 128;
    int n0 = blockIdx.y * 128;
    int b = n0 >> 12, s0 = n0 & 4095;
    const float* zb = z + (size_t)b * ZBATCH + s0;
    int tx = tid & 15, ty = tid >> 4;

    float acc[8][8];
    #pragma unroll
    for (int i = 0; i < 8; ++i)
        #pragma unroll
        for (int j = 0; j < 8; ++j) acc[i][j] = 0.0f;

    for (int step = 0; step < 8; ++step){
        int c0 = step * 32;
        #pragma unroll
        for (int r = 0; r < 16; ++r){
            int ii = r * TPB + tid;
            int c = ii >> 7, i = ii & 127;
            As[c][i] = zb[(size_t)(c0 + c) * SPAT + i];     // coalesced over i
        }
        #pragma unroll
        for (int r = 0; r < 16; ++r){
            int ii = r * TPB + tid;
            int c = ii & 31, j = ii >> 5;
            Bs[c][j] = W[(k0 + j) * DDIM + c0 + c];         // coalesced over c
        }
        __syncthreads();
        #pragma unroll
        for (int kk = 0; kk < 32; ++kk){
            float av[8], bv[8];
            float4 a0 = *(const float4*)&As[kk][ty*8];
            float4 a1 = *(const float4*)&As[kk][ty*8+4];
            float4 b0 = *(const float4*)&Bs[kk][tx*8];
            float4 b1 = *(const float4*)&Bs[kk][tx*8+4];
            av[0]=a0.x; av[1]=a0.y; av[2]=a0.z; av[3]=a0.w;
            av[4]=a1.x; av[5]=a1.y; av[6]=a1.z; av[7]=a1.w;
            bv[0]=b0.x; bv[1]=b0.y; bv[2]=b0.z; bv[3]=b0.w;
            bv[4]=b1.x; bv[5]=b1.y; bv[6]=b1.z; bv[7]=b1.w;
            #pragma unroll
            for (int i = 0; i < 8; ++i)
                #pragma unroll
                for (int j = 0; j < 8; ++j)
                    acc[i][j] += av[i] * bv[j];
        }
        __syncthreads();
    }
    #pragma unroll
    for (int i = 0; i < 8; ++i){
        int n = n0 + ty*8 + i;
        float sc = invn[n];
        float4 o0, o1;
        o0.x = acc[i][0]*sc; o0.y = acc[i][1]*sc; o0.z = acc[i][2]*sc; o0.w = acc[i][3]*sc;
        o1.x = acc[i][4]*sc; o1.y = acc[i][5]*sc; o1.z = acc[i][6]*sc; o1.w = acc[i][7]*sc;
        float* dst = L + (size_t)n * KCB + k0 + tx*8;
        *(float4*)dst       = o0;
        *(float4*)(dst + 4) = o1;
    }
}

// ---------------- Sinkhorn row pass: R[k] += sum_n exp(L/eps)*b[n] ----------------
__global__ __launch_bounds__(TPB) void vq_row_kernel(const float* __restrict__ L, const float* __restrict__ bvec,
                                                     float* __restrict__ R){
    __shared__ float bsh[128];
    int tid = threadIdx.x;
    int k0 = blockIdx.x * 512;
    int n0 = blockIdx.y * 128;
    if (tid < 128) bsh[tid] = bvec[n0 + tid];
    __syncthreads();
    const float* Lp = L + (size_t)n0 * KCB + k0 + tid*2;
    float r0 = 0.0f, r1 = 0.0f;
    for (int nn = 0; nn < 128; ++nn){
        float2 v = *(const float2*)Lp;
        float bb = bsh[nn];
        r0 += expf(v.x * INV_EPS) * bb;   // accurate expf: feeds a_k -> argmax
        r1 += expf(v.y * INV_EPS) * bb;
        Lp += KCB;
    }
    atomicAdd(&R[k0 + tid*2],     r0);
    atomicAdd(&R[k0 + tid*2 + 1], r1);
}

// ---------------- Sinkhorn col pass (iters 1,2): b[n] = 1/(N * sum_k exp(L/eps)*a_k) ----------------
__global__ __launch_bounds__(TPB) void vq_col12_kernel(const float* __restrict__ L, const float* __restrict__ R,
                                                       float* __restrict__ bvec){
    __shared__ float ash[KCB];
    int tid = threadIdx.x;
    for (int t = tid; t < KCB; t += TPB) ash[t] = 1.0f / (1024.0f * R[t]);
    __syncthreads();
    int lane = tid & 63, w = tid >> 6;
    float areg[16];
    #pragma unroll
    for (int j = 0; j < 4; ++j){
        float4 a4 = *(const float4*)&ash[j*256 + lane*4];
        areg[j*4+0]=a4.x; areg[j*4+1]=a4.y; areg[j*4+2]=a4.z; areg[j*4+3]=a4.w;
    }
    int n0 = blockIdx.x * 16;
    for (int r = 0; r < 4; ++r){
        int n = n0 + w*4 + r;
        const float4* row = (const float4*)(L + (size_t)n * KCB);
        float c = 0.0f;
        #pragma unroll
        for (int j = 0; j < 4; ++j){
            float4 v = row[j*64 + lane];
            c += areg[j*4+0] * expf(v.x * INV_EPS);
            c += areg[j*4+1] * expf(v.y * INV_EPS);
            c += areg[j*4+2] * expf(v.z * INV_EPS);
            c += areg[j*4+3] * expf(v.w * INV_EPS);
        }
        #pragma unroll
        for (int m = 1; m < 64; m <<= 1) c += __shfl_xor(c, m);
        if (lane == 0) bvec[n] = 1.0f / (32768.0f * c);
    }
}

// ---------------- final col pass fused: b, softmax lse, loss, argmax, counts ----------------
__global__ __launch_bounds__(TPB) void vq_col3_kernel(const float* __restrict__ L, const float* __restrict__ R,
                                                      int* __restrict__ counts, int* __restrict__ idx,
                                                      float* __restrict__ loss_acc){
    __shared__ float ash[KCB];
    int tid = threadIdx.x;
    for (int t = tid; t < KCB; t += TPB) ash[t] = 1.0f / (1024.0f * R[t]);
    __syncthreads();
    int lane = tid & 63, w = tid >> 6;
    float areg[16];
    #pragma unroll
    for (int j = 0; j < 4; ++j){
        float4 a4 = *(const float4*)&ash[j*256 + lane*4];
        areg[j*4+0]=a4.x; areg[j*4+1]=a4.y; areg[j*4+2]=a4.z; areg[j*4+3]=a4.w;
    }
    int n0 = blockIdx.x * 16;
    float lossw = 0.0f;
    for (int r = 0; r < 4; ++r){
        int n = n0 + w*4 + r;
        const float4* row = (const float4*)(L + (size_t)n * KCB);
        float4 v[4];
        #pragma unroll
        for (int j = 0; j < 4; ++j) v[j] = row[j*64 + lane];

        float ea[16];
        float csum = 0.0f, mrow = -1e30f;
        #pragma unroll
        for (int j = 0; j < 4; ++j){
            float e;
            e = expf(v[j].x * INV_EPS) * areg[j*4+0]; ea[j*4+0]=e; csum+=e; mrow=fmaxf(mrow, v[j].x);
            e = expf(v[j].y * INV_EPS) * areg[j*4+1]; ea[j*4+1]=e; csum+=e; mrow=fmaxf(mrow, v[j].y);
            e = expf(v[j].z * INV_EPS) * areg[j*4+2]; ea[j*4+2]=e; csum+=e; mrow=fmaxf(mrow, v[j].z);
            e = expf(v[j].w * INV_EPS) * areg[j*4+3]; ea[j*4+3]=e; csum+=e; mrow=fmaxf(mrow, v[j].w);
        }
        #pragma unroll
        for (int m = 1; m < 64; m <<= 1){
            csum += __shfl_xor(csum, m);
            mrow = fmaxf(mrow, __shfl_xor(mrow, m));
        }
        // argmax of q (== argmax of E*a within a row), np.argmax tie-break: lowest k
        float bv = -1.0f; int bk = 0;
        #pragma unroll
        for (int j = 0; j < 4; ++j){
            #pragma unroll
            for (int mm = 0; mm < 4; ++mm){
                float e = ea[j*4+mm];
                int k = j*256 + lane*4 + mm;
                if (e > bv){ bv = e; bk = k; }
            }
        }
        #pragma unroll
        for (int m = 1; m < 64; m <<= 1){
            float ov = __shfl_xor(bv, m); int ok = __shfl_xor(bk, m);
            if (ov > bv || (ov == bv && ok < bk)){ bv = ov; bk = ok; }
        }
        // softmax denom for p (with row-max subtraction, as jax.nn.softmax does)
        float ssum = 0.0f;
        #pragma unroll
        for (int j = 0; j < 4; ++j){
            ssum += __expf((v[j].x - mrow) * INV_T);
            ssum += __expf((v[j].y - mrow) * INV_T);
            ssum += __expf((v[j].z - mrow) * INV_T);
            ssum += __expf((v[j].w - mrow) * INV_T);
        }
        #pragma unroll
        for (int m = 1; m < 64; m <<= 1) ssum += __shfl_xor(ssum, m);
        float rs = 1.0f / ssum;
        float cinv = 1.0f / csum;
        #pragma unroll
        for (int j = 0; j < 4; ++j){
            float p, q;
            p = __expf((v[j].x - mrow) * INV_T) * rs; q = ea[j*4+0] * cinv; lossw += q * __logf(p + 1e-6f);
            p = __expf((v[j].y - mrow) * INV_T) * rs; q = ea[j*4+1] * cinv; lossw += q * __logf(p + 1e-6f);
            p = __expf((v[j].z - mrow) * INV_T) * rs; q = ea[j*4+2] * cinv; lossw += q * __logf(p + 1e-6f);
            p = __expf((v[j].w - mrow) * INV_T) * rs; q = ea[j*4+3] * cinv; lossw += q * __logf(p + 1e-6f);
        }
        if (lane == 0){
            idx[n] = bk;
            atomicAdd(&counts[bk], 1);
        }
    }
    #pragma unroll
    for (int m = 1; m < 64; m <<= 1) lossw += __shfl_xor(lossw, m);
    if (lane == 0) atomicAdd(loss_acc, lossw);
}

// ---------------- finalize: loss + unique ----------------
__global__ __launch_bounds__(TPB) void vq_finalize_kernel(const int* __restrict__ counts,
                                                          const float* __restrict__ loss_acc,
                                                          float* __restrict__ out){
    __shared__ int red[TPB];
    int tid = threadIdx.x;
    int cnt = 0;
    for (int t = tid; t < KCB; t += TPB) cnt += (counts[t] > 0) ? 1 : 0;
    red[tid] = cnt;
    __syncthreads();
    for (int s = TPB/2; s > 0; s >>= 1){
        if (tid < s) red[tid] += red[tid + s];
        __syncthreads();
    }
    if (tid == 0){
        out[8388608] = -loss_acc[0] / 33554432.0f;   // -mean over N*K
        out[8388609] = (float)red[0];
    }
}

// ---------------- z_q gather: out[b][c][s] = W[idx[b*4096+s]][c] ----------------
__global__ __launch_bounds__(TPB) void vq_zq_kernel(const float* __restrict__ W, const int* __restrict__ idx,
                                                    float* __restrict__ out){
    int o = blockIdx.x * TPB + threadIdx.x;   // 8388608 total
    int s = o & 4095;
    int rem = o >> 12;
    int c = rem & 255;
    int b = rem >> 8;
    int n = (b << 12) + s;
    out[o] = W[idx[n] * DDIM + c];
}

extern "C" void kernel_launch(void* const* d_in, const int* in_sizes, int n_in,
                              void* d_out, int out_size, void* d_ws, size_t ws_size,
                              hipStream_t stream) {
    const float* z = (const float*)d_in[0];
    const float* W = (const float*)d_in[1];
    float* out = (float*)d_out;
    float* ws = (float*)d_ws;

    // ws layout (floats)
    float* L      = ws;                        // 33554432
    float* invn   = ws + 33554432;             // 32768
    float* bvec   = invn + 32768;              // 32768
    float* R      = bvec + 32768;              // 3*1024
    int*   counts = (int*)(R + 3*KCB);         // 1024
    int*   idx    = counts + KCB;              // 32768
    float* loss   = (float*)(idx + NTOT);      // 1

    vq_init_kernel<<<128, TPB, 0, stream>>>(bvec, R, counts, loss);
    vq_norms_kernel<<<NTOT/TPB, TPB, 0, stream>>>(z, invn);
    vq_gemm_kernel<<<dim3(KCB/128, NTOT/128), TPB, 0, stream>>>(z, W, invn, L);

    vq_row_kernel<<<dim3(2, 256), TPB, 0, stream>>>(L, bvec, R);
    vq_col12_kernel<<<NTOT/16, TPB, 0, stream>>>(L, R, bvec);
    vq_row_kernel<<<dim3(2, 256), TPB, 0, stream>>>(L, bvec, R + KCB);
    vq_col12_kernel<<<NTOT/16, TPB, 0, stream>>>(L, R + KCB, bvec);
    vq_row_kernel<<<dim3(2, 256), TPB, 0, stream>>>(L, bvec, R + 2*KCB);
    vq_col3_kernel<<<NTOT/16, TPB, 0, stream>>>(L, R + 2*KCB, counts, idx, loss);

    vq_finalize_kernel<<<1, TPB, 0, stream>>>(counts, loss, out);
    vq_zq_kernel<<<8388608/TPB, TPB, 0, stream>>>(W, idx, out);
}

// Round 2
// 384.756 us; speedup vs baseline: 1.6604x; 1.6604x over previous
//
#include <hip/hip_runtime.h>
#include <math.h>

typedef float    f32x4  __attribute__((ext_vector_type(4)));
typedef short    bf16x8 __attribute__((ext_vector_type(8)));
typedef _Float16 h16x8  __attribute__((ext_vector_type(8)));

#define NTOT 32768      // samples
#define KCB  1024       // codebook
#define DDIM 256        // dim
#define SPAT 4096
#define ZB   1048576
#define INV_EPS 20.0f
#define INV_T   10.0f

__device__ __forceinline__ unsigned short f2bf(float f){
    unsigned u = __builtin_bit_cast(unsigned, f);
    u += 0x7fffu + ((u >> 16) & 1u);
    return (unsigned short)(u >> 16);
}

// ---------------- init: zero counts + loss ----------------
__global__ __launch_bounds__(256) void vq_init(int* __restrict__ counts, float* __restrict__ loss){
    int t = threadIdx.x;
    #pragma unroll
    for (int i = 0; i < 4; ++i) counts[i*256 + t] = 0;
    if (t == 0) loss[0] = 0.0f;
}

// ---------------- prepA: z -> fragment-major bf16 A + invn ----------------
// A layout: frag blocks [G=2048 row-groups][cc=8][lane=64] of 8 bf16 (8 consecutive c)
// frag element: A[16*G + (lane&15)][32*cc + (lane>>4)*8 + j]
__global__ __launch_bounds__(256) void vq_prepA(const float* __restrict__ z, bf16x8* __restrict__ Ab,
                                                float* __restrict__ invn){
    __shared__ unsigned short lds[256][68];   // [c][s], padded
    __shared__ float sbuf[4][64];
    int tid = threadIdx.x, lane = tid & 63, w = tid >> 6;
    int bid = blockIdx.x;
    int n0 = bid * 64, b = n0 >> 12, s0 = n0 & 4095;
    const float* zb = z + (size_t)b * ZB + s0;
    int col4 = tid & 15;
    float sq0 = 0.f, sq1 = 0.f, sq2 = 0.f, sq3 = 0.f;
    #pragma unroll
    for (int it = 0; it < 16; ++it){
        int c = it*16 + (tid >> 4);
        float4 v = *(const float4*)(zb + (size_t)c * SPAT + col4*4);
        sq0 += v.x*v.x; sq1 += v.y*v.y; sq2 += v.z*v.z; sq3 += v.w*v.w;
        unsigned long long pk = (unsigned long long)f2bf(v.x)
                              | ((unsigned long long)f2bf(v.y) << 16)
                              | ((unsigned long long)f2bf(v.z) << 32)
                              | ((unsigned long long)f2bf(v.w) << 48);
        *(unsigned long long*)&lds[c][col4*4] = pk;
    }
    sq0 += __shfl_xor(sq0,16); sq0 += __shfl_xor(sq0,32);
    sq1 += __shfl_xor(sq1,16); sq1 += __shfl_xor(sq1,32);
    sq2 += __shfl_xor(sq2,16); sq2 += __shfl_xor(sq2,32);
    sq3 += __shfl_xor(sq3,16); sq3 += __shfl_xor(sq3,32);
    if (lane < 16){
        sbuf[w][lane*4+0] = sq0; sbuf[w][lane*4+1] = sq1;
        sbuf[w][lane*4+2] = sq2; sbuf[w][lane*4+3] = sq3;
    }
    __syncthreads();
    if (tid < 64){
        float t = sbuf[0][tid] + sbuf[1][tid] + sbuf[2][tid] + sbuf[3][tid];
        invn[n0 + tid] = 1.0f / fmaxf(sqrtf(t), 1e-12f);
    }
    #pragma unroll
    for (int i = 0; i < 8; ++i){
        int x = i*4 + (tid >> 6);         // g*8 + cc, 0..31
        int cc = x & 7, g = x >> 3;
        int srow = g*16 + (lane & 15);
        int cbase = cc*32 + (lane >> 4)*8;
        bf16x8 fr;
        #pragma unroll
        for (int j = 0; j < 8; ++j) fr[j] = (short)lds[cbase + j][srow];
        Ab[(size_t)bid*2048 + i*256 + tid] = fr;
    }
}

// ---------------- prepB: W -> fragment-major bf16 B ----------------
__global__ __launch_bounds__(256) void vq_prepB(const float* __restrict__ W, bf16x8* __restrict__ Bb){
    int slot = blockIdx.x*256 + threadIdx.x;   // 32768
    int l = slot & 63, x = slot >> 6;
    int cc = x & 7, kg = x >> 3;
    int krow = kg*16 + (l & 15);
    int cbase = cc*32 + (l >> 4)*8;
    const float* wp = W + (size_t)krow*DDIM + cbase;
    float4 v0 = *(const float4*)wp, v1 = *(const float4*)(wp + 4);
    bf16x8 fr;
    fr[0] = (short)f2bf(v0.x); fr[1] = (short)f2bf(v0.y);
    fr[2] = (short)f2bf(v0.z); fr[3] = (short)f2bf(v0.w);
    fr[4] = (short)f2bf(v1.x); fr[5] = (short)f2bf(v1.y);
    fr[6] = (short)f2bf(v1.z); fr[7] = (short)f2bf(v1.w);
    Bb[slot] = fr;
}

// ---------------- MFMA GEMM: L[n][k] f16, + per-block colsum(E) partials ----------------
__global__ __launch_bounds__(256) void vq_gemm(const bf16x8* __restrict__ Ab, const bf16x8* __restrict__ Bb,
                                               const float* __restrict__ invn, _Float16* __restrict__ Lh,
                                               float* __restrict__ P1){
    __shared__ float Rsh[128];
    int tid = threadIdx.x, lane = tid & 63, w = tid >> 6;
    int wm = w >> 1, wn = w & 1;
    int bk = blockIdx.x, bm = blockIdx.y;
    if (tid < 128) Rsh[tid] = 0.0f;
    const bf16x8* Ap = Ab + (size_t)(bm*8 + wm*4)*512 + lane;
    const bf16x8* Bp = Bb + (size_t)(bk*8 + wn*4)*512 + lane;
    f32x4 zero4 = {0.f, 0.f, 0.f, 0.f};
    f32x4 acc[4][4];
    #pragma unroll
    for (int i = 0; i < 4; ++i)
        #pragma unroll
        for (int j = 0; j < 4; ++j) acc[i][j] = zero4;
    bf16x8 aF[2][4], bF[2][4];
    #pragma unroll
    for (int i = 0; i < 4; ++i){ aF[0][i] = Ap[i*512]; bF[0][i] = Bp[i*512]; }
    #pragma unroll
    for (int cc = 0; cc < 8; ++cc){
        int cur = cc & 1, nxt = cur ^ 1;
        if (cc < 7){
            #pragma unroll
            for (int i = 0; i < 4; ++i){
                aF[nxt][i] = Ap[i*512 + (cc+1)*64];
                bF[nxt][i] = Bp[i*512 + (cc+1)*64];
            }
        }
        #pragma unroll
        for (int i = 0; i < 4; ++i)
            #pragma unroll
            for (int j = 0; j < 4; ++j)
                acc[i][j] = __builtin_amdgcn_mfma_f32_16x16x32_bf16(aF[cur][i], bF[cur][j], acc[i][j], 0, 0, 0);
    }
    // epilogue: scale, f16 round, store L, accumulate col-sums of E
    float invr[4][4];
    int rbase = bm*128 + wm*64 + (lane >> 4)*4;
    #pragma unroll
    for (int i = 0; i < 4; ++i)
        #pragma unroll
        for (int r = 0; r < 4; ++r) invr[i][r] = invn[rbase + i*16 + r];
    int cbase = bk*128 + wn*64 + (lane & 15);
    float cs[4] = {0.f, 0.f, 0.f, 0.f};
    #pragma unroll
    for (int j = 0; j < 4; ++j){
        #pragma unroll
        for (int i = 0; i < 4; ++i){
            #pragma unroll
            for (int r = 0; r < 4; ++r){
                float val = acc[i][j][r] * invr[i][r];
                _Float16 vh = (_Float16)val;
                cs[j] += __expf((float)vh * INV_EPS);
                Lh[(size_t)(rbase + i*16 + r)*KCB + cbase + j*16] = vh;
            }
        }
        cs[j] += __shfl_xor(cs[j], 16);
        cs[j] += __shfl_xor(cs[j], 32);
    }
    __syncthreads();
    if (lane < 16){
        #pragma unroll
        for (int j = 0; j < 4; ++j) atomicAdd(&Rsh[wn*64 + j*16 + lane], cs[j]);
    }
    __syncthreads();
    if (tid < 128) P1[(size_t)bm*KCB + bk*128 + tid] = Rsh[tid];
}

// ---------------- reduce: a[k] = 1/(1024 * sum_rows P[r][k]) ----------------
__global__ __launch_bounds__(256) void vq_reduce(const float* __restrict__ P, int nrows, float* __restrict__ aout){
    __shared__ float red[8][32];
    int tid = threadIdx.x, kl = tid & 31, rg = tid >> 5;
    int k0 = blockIdx.x * 32;
    float s = 0.f;
    for (int r = rg; r < nrows; r += 8) s += P[(size_t)r*KCB + k0 + kl];
    red[rg][kl] = s;
    __syncthreads();
    if (tid < 32){
        float t = 0.f;
        #pragma unroll
        for (int g = 0; g < 8; ++g) t += red[g][tid];
        aout[k0 + tid] = 1.0f / (1024.0f * t);
    }
}

// ---------------- fused col-normalize + next row-sum partials ----------------
__global__ __launch_bounds__(256) void vq_colrow(const _Float16* __restrict__ Lh, const float* __restrict__ avec,
                                                 float* __restrict__ P){
    __shared__ float ash[1024];
    __shared__ float Rsh[1024];
    int tid = threadIdx.x, lane = tid & 63, w = tid >> 6;
    ((float4*)ash)[tid] = ((const float4*)avec)[tid];
    float4 z4 = {0.f, 0.f, 0.f, 0.f};
    ((float4*)Rsh)[tid] = z4;
    __syncthreads();
    float aL[16];
    #pragma unroll
    for (int j = 0; j < 8; ++j){ aL[j] = ash[lane*8 + j]; aL[8+j] = ash[512 + lane*8 + j]; }
    float racc[16];
    #pragma unroll
    for (int j = 0; j < 16; ++j) racc[j] = 0.f;
    int n0 = blockIdx.x*32 + w*8;
    const h16x8* base = (const h16x8*)Lh;
    h16x8 c0 = base[(size_t)n0*128 + lane];
    h16x8 c1 = base[(size_t)n0*128 + 64 + lane];
    #pragma unroll
    for (int rr = 0; rr < 8; ++rr){
        h16x8 d0, d1;
        if (rr < 7){
            d0 = base[(size_t)(n0+rr+1)*128 + lane];
            d1 = base[(size_t)(n0+rr+1)*128 + 64 + lane];
        }
        float e[16], csum = 0.f;
        #pragma unroll
        for (int j = 0; j < 8; ++j){ e[j]   = __expf((float)c0[j] * INV_EPS); csum += e[j]  *aL[j];   }
        #pragma unroll
        for (int j = 0; j < 8; ++j){ e[8+j] = __expf((float)c1[j] * INV_EPS); csum += e[8+j]*aL[8+j]; }
        #pragma unroll
        for (int m = 1; m < 64; m <<= 1) csum += __shfl_xor(csum, m);
        float bn = 1.0f / (32768.0f * csum);
        #pragma unroll
        for (int j = 0; j < 16; ++j) racc[j] += e[j]*bn;
        if (rr < 7){ c0 = d0; c1 = d1; }
    }
    #pragma unroll
    for (int j = 0; j < 8; ++j){
        atomicAdd(&Rsh[lane*8 + j], racc[j]);
        atomicAdd(&Rsh[512 + lane*8 + j], racc[8+j]);
    }
    __syncthreads();
    ((float4*)(P + (size_t)blockIdx.x*KCB))[tid] = ((float4*)Rsh)[tid];
}

// ---------------- final pass: argmax, counts, loss ----------------
__global__ __launch_bounds__(256) void vq_final(const _Float16* __restrict__ Lh, const float* __restrict__ a3,
                                                int* __restrict__ counts, int* __restrict__ idx,
                                                float* __restrict__ loss_acc){
    __shared__ float ash[1024];
    int tid = threadIdx.x, lane = tid & 63, w = tid >> 6;
    ((float4*)ash)[tid] = ((const float4*)a3)[tid];
    __syncthreads();
    float aL[16];
    #pragma unroll
    for (int j = 0; j < 8; ++j){ aL[j] = ash[lane*8 + j]; aL[8+j] = ash[512 + lane*8 + j]; }
    int n0 = blockIdx.x*32 + w*8;
    const h16x8* base = (const h16x8*)Lh;
    float lossw = 0.f;
    #pragma unroll 1
    for (int rr = 0; rr < 8; ++rr){
        int n = n0 + rr;
        h16x8 c0 = base[(size_t)n*128 + lane];
        h16x8 c1 = base[(size_t)n*128 + 64 + lane];
        float Lf[16], s[16];
        #pragma unroll
        for (int j = 0; j < 8; ++j){ Lf[j] = (float)c0[j]; Lf[8+j] = (float)c1[j]; }
        float csum = 0.f, mrow = -1e30f;
        #pragma unroll
        for (int j = 0; j < 16; ++j){
            float e = __expf(Lf[j] * INV_EPS);
            s[j] = e * aL[j];
            csum += s[j];
            mrow = fmaxf(mrow, Lf[j]);
        }
        #pragma unroll
        for (int m = 1; m < 64; m <<= 1){
            csum += __shfl_xor(csum, m);
            mrow = fmaxf(mrow, __shfl_xor(mrow, m));
        }
        float bv = s[0]; int bk = lane*8;
        #pragma unroll
        for (int j = 1; j < 16; ++j){
            int k = (j < 8) ? (lane*8 + j) : (512 + lane*8 + (j - 8));
            if (s[j] > bv){ bv = s[j]; bk = k; }
        }
        #pragma unroll
        for (int m = 1; m < 64; m <<= 1){
            float ov = __shfl_xor(bv, m); int ok = __shfl_xor(bk, m);
            if (ov > bv || (ov == bv && ok < bk)){ bv = ov; bk = ok; }
        }
        float ssum = 0.f;
        #pragma unroll
        for (int j = 0; j < 16; ++j) ssum += __expf((Lf[j] - mrow) * INV_T);
        #pragma unroll
        for (int m = 1; m < 64; m <<= 1) ssum += __shfl_xor(ssum, m);
        float rs = 1.0f / ssum, ci = 1.0f / csum;
        #pragma unroll
        for (int j = 0; j < 16; ++j)
            lossw += (s[j] * ci) * __logf(__expf((Lf[j] - mrow) * INV_T) * rs + 1e-6f);
        if (lane == 0){ idx[n] = bk; atomicAdd(&counts[bk], 1); }
    }
    #pragma unroll
    for (int m = 1; m < 64; m <<= 1) lossw += __shfl_xor(lossw, m);
    if (lane == 0) atomicAdd(loss_acc, lossw);
}

// ---------------- finalize: loss + unique ----------------
__global__ __launch_bounds__(256) void vq_finalize(const int* __restrict__ counts,
                                                   const float* __restrict__ loss_acc,
                                                   float* __restrict__ out){
    __shared__ int red[256];
    int t = threadIdx.x, c = 0;
    #pragma unroll
    for (int i = 0; i < 4; ++i) c += (counts[i*256 + t] > 0) ? 1 : 0;
    red[t] = c;
    __syncthreads();
    for (int s = 128; s > 0; s >>= 1){
        if (t < s) red[t] += red[t + s];
        __syncthreads();
    }
    if (t == 0){
        out[8388608] = -loss_acc[0] / 33554432.0f;
        out[8388609] = (float)red[0];
    }
}

// ---------------- z_q gather ----------------
__global__ __launch_bounds__(256) void vq_zq(const float* __restrict__ W, const int* __restrict__ idx,
                                             float* __restrict__ out){
    int gid = blockIdx.x*256 + threadIdx.x;
    int o = gid*4;
    int s = o & 4095, rem = o >> 12, c = rem & 255, b = rem >> 8;
    const int4 iv = *(const int4*)(idx + (b << 12) + s);
    float4 ov;
    ov.x = W[(size_t)iv.x*DDIM + c];
    ov.y = W[(size_t)iv.y*DDIM + c];
    ov.z = W[(size_t)iv.z*DDIM + c];
    ov.w = W[(size_t)iv.w*DDIM + c];
    *(float4*)(out + o) = ov;
}

extern "C" void kernel_launch(void* const* d_in, const int* in_sizes, int n_in,
                              void* d_out, int out_size, void* d_ws, size_t ws_size,
                              hipStream_t stream) {
    const float* z = (const float*)d_in[0];
    const float* W = (const float*)d_in[1];
    float* out = (float*)d_out;
    char* ws = (char*)d_ws;

    // ws layout (bytes)
    _Float16* Lh   = (_Float16*)(ws);                       // 67,108,864
    bf16x8*   Ab   = (bf16x8*)(ws + 67108864);              // 16,777,216
    bf16x8*   Bb   = (bf16x8*)(ws + 83886080);              //    524,288
    float*    invn = (float*)(ws + 84410368);               //    131,072
    float*    P1   = (float*)(ws + 84541440);               //  1,048,576 (256x1024)
    float*    P    = (float*)(ws + 85590016);               //  4,194,304 (1024x1024)
    float*    a1   = (float*)(ws + 89784320);               //      4,096
    float*    a2   = (float*)(ws + 89788416);
    float*    a3   = (float*)(ws + 89792512);
    int*      counts = (int*)(ws + 89796608);               //      4,096
    int*      idx    = (int*)(ws + 89800704);               //    131,072
    float*    loss   = (float*)(ws + 89931776);             //          4

    vq_init<<<1, 256, 0, stream>>>(counts, loss);
    vq_prepA<<<512, 256, 0, stream>>>(z, Ab, invn);
    vq_prepB<<<128, 256, 0, stream>>>(W, Bb);
    vq_gemm<<<dim3(8, 256), 256, 0, stream>>>(Ab, Bb, invn, Lh, P1);
    vq_reduce<<<32, 256, 0, stream>>>(P1, 256, a1);
    vq_colrow<<<1024, 256, 0, stream>>>(Lh, a1, P);
    vq_reduce<<<32, 256, 0, stream>>>(P, 1024, a2);
    vq_colrow<<<1024, 256, 0, stream>>>(Lh, a2, P);
    vq_reduce<<<32, 256, 0, stream>>>(P, 1024, a3);
    vq_final<<<1024, 256, 0, stream>>>(Lh, a3, counts, idx, loss);
    vq_finalize<<<1, 256, 0, stream>>>(counts, loss, out);
    vq_zq<<<8192, 256, 0, stream>>>(W, idx, out);
}